// Round 4
// baseline (196.275 us; speedup 1.0000x reference)
//
#include <hip/hip_runtime.h>

#define BATCH 4
#define CH    256
#define SVOL  32768   // 32*32*32
#define SV4   8192    // SVOL/4
#define TILE  64      // spatial float4 positions per block
#define NCH   4       // channel chunks per block
#define CCH   64      // channels per chunk (contiguous -> 1KB wave loads)

typedef float floatx4 __attribute__((ext_vector_type(4)));
typedef float floatx2 __attribute__((ext_vector_type(2)));

// ws layout (floats):
//   [0, 1024)           coef[b][c]
//   [1024, +BATCH*SVOL) small[b][s]   (512 KB)

__global__ void __launch_bounds__(256)
coef_kernel(const float* __restrict__ istyle,
            const float* __restrict__ W_style,
            const float* __restrict__ b_style,
            const float* __restrict__ wk,
            float* __restrict__ coef) {
    int tid  = threadIdx.x;
    int wave = blockIdx.x * 4 + (tid >> 6);   // 0..1023
    int lane = tid & 63;
    int b = wave >> 8;
    int c = wave & 255;
    const float* is = istyle + b * 512;
    const float* wr = W_style + c * 512;
    float acc = 0.f;
    #pragma unroll
    for (int j = 0; j < 8; ++j) {
        int k = lane + j * 64;
        acc += is[k] * wr[k];
    }
    #pragma unroll
    for (int off = 32; off >= 1; off >>= 1)
        acc += __shfl_down(acc, off, 64);
    if (lane == 0)
        coef[b * 256 + c] = wk[c] * (acc + b_style[c] + 1.0f);
}

// One block: TILE=64 float4 positions x all 256 channels.
// thread t: pos = t & 63, chunk = t >> 6 (64 contiguous channels each).
// Every wave load = one contiguous 1KB segment. LDS-reduce 4 chunks,
// add prev, write small.
__global__ void __launch_bounds__(256)
reduce_c_kernel(const floatx4* __restrict__ x4,
                const float* __restrict__ coef,
                const floatx4* __restrict__ prev4,
                floatx4* __restrict__ small4) {
    __shared__ float   cf[CH];
    __shared__ floatx4 red[NCH][TILE];

    int t     = threadIdx.x;
    int pos   = t & (TILE - 1);
    int chunk = t >> 6;
    int gpos  = blockIdx.x * TILE + pos;      // 0..BATCH*SV4-1
    int b     = gpos >> 13;                   // / SV4
    int s4    = gpos & (SV4 - 1);

    cf[t] = coef[b * CH + t];                 // all 256 coef for this b
    __syncthreads();

    const floatx4* xp = x4 + (size_t)(b * CH + chunk * CCH) * SV4 + s4;
    floatx4 acc = {0.f, 0.f, 0.f, 0.f};
    #pragma unroll 16
    for (int cc = 0; cc < CCH; ++cc) {
        floatx4 v = __builtin_nontemporal_load(&xp[(size_t)cc * SV4]);
        float   w = cf[chunk * CCH + cc];
        acc += v * w;
    }
    red[chunk][pos] = acc;
    __syncthreads();

    if (t < TILE) {
        floatx4 r = prev4[gpos];
        #pragma unroll
        for (int k = 0; k < NCH; ++k)
            r += red[k][t];
        small4[gpos] = r;
    }
}

// Fused 2x trilinear upsample + [1,2,1]^3/64 blur as a separable 3-tap
// stencil on the SMALL grid: even o=2j -> (5,10,1)/16, odd -> (1,10,5)/16,
// edge-clamped; final scale 1/4096. Each thread computes the full 2x2x2
// output octet of one small-grid cell from its 3^3 neighborhood:
// 27 loads -> 8 outputs, float2 stores.
__global__ void __launch_bounds__(256)
upblur_kernel(const float* __restrict__ small,
              float* __restrict__ out) {
    int u  = blockIdx.x * 256 + threadIdx.x;  // 0..BATCH*32^3-1
    int jx = u & 31;
    int jy = (u >> 5) & 31;
    int jz = (u >> 10) & 31;
    int b  = u >> 15;

    int xm = jx > 0 ? jx - 1 : 0, xp_ = jx < 31 ? jx + 1 : 31;
    int ym = jy > 0 ? jy - 1 : 0, yp_ = jy < 31 ? jy + 1 : 31;
    int zm = jz > 0 ? jz - 1 : 0, zp_ = jz < 31 ? jz + 1 : 31;
    int zi[3] = { zm, jz, zp_ };
    int yi[3] = { ym, jy, yp_ };
    int xi[3] = { xm, jx, xp_ };

    const float* base = small + (size_t)b * SVOL;

    // x-combine while loading: for each (a,c) produce even/odd x sums
    float ex[3][3], ox[3][3];
    #pragma unroll
    for (int a = 0; a < 3; ++a) {
        const float* pz = base + zi[a] * 1024;
        #pragma unroll
        for (int c = 0; c < 3; ++c) {
            const float* py = pz + yi[c] * 32;
            float v0 = py[xi[0]], v1 = py[xi[1]], v2 = py[xi[2]];
            float m = 10.f * v1;
            ex[a][c] = 5.f * v0 + m + v2;
            ox[a][c] = v0 + m + 5.f * v2;
        }
    }
    // y-combine
    float eye[3], eyo[3], oye[3], oyo[3];  // [a], (py,px) = (e,e),(e,o),(o,e),(o,o)
    #pragma unroll
    for (int a = 0; a < 3; ++a) {
        float me = 10.f * ex[a][1], mo = 10.f * ox[a][1];
        eye[a] = 5.f * ex[a][0] + me + ex[a][2];
        eyo[a] = 5.f * ox[a][0] + mo + ox[a][2];
        oye[a] = ex[a][0] + me + 5.f * ex[a][2];
        oyo[a] = ox[a][0] + mo + 5.f * ox[a][2];
    }
    // z-combine -> 8 outputs
    const float s = 1.0f / 4096.0f;
    float z0ee = (5.f * eye[0] + 10.f * eye[1] + eye[2]) * s;
    float z0eo = (5.f * eyo[0] + 10.f * eyo[1] + eyo[2]) * s;
    float z0oe = (5.f * oye[0] + 10.f * oye[1] + oye[2]) * s;
    float z0oo = (5.f * oyo[0] + 10.f * oyo[1] + oyo[2]) * s;
    float z1ee = (eye[0] + 10.f * eye[1] + 5.f * eye[2]) * s;
    float z1eo = (eyo[0] + 10.f * eyo[1] + 5.f * eyo[2]) * s;
    float z1oe = (oye[0] + 10.f * oye[1] + 5.f * oye[2]) * s;
    float z1oo = (oyo[0] + 10.f * oyo[1] + 5.f * oyo[2]) * s;

    // out[b][zo][yo][xo], zo=2jz+pz etc. float2 stores along x.
    size_t obase = (size_t)b * 262144 + (size_t)(2 * jz) * 4096 + (size_t)(2 * jy) * 64 + 2 * jx;
    floatx2* o0 = (floatx2*)(out + obase);
    floatx2* o1 = (floatx2*)(out + obase + 64);    // py=1
    floatx2* o2 = (floatx2*)(out + obase + 4096);  // pz=1
    floatx2* o3 = (floatx2*)(out + obase + 4160);  // pz=1,py=1
    *o0 = (floatx2){z0ee, z0eo};
    *o1 = (floatx2){z0oe, z0oo};
    *o2 = (floatx2){z1ee, z1eo};
    *o3 = (floatx2){z1oe, z1oo};
}

extern "C" void kernel_launch(void* const* d_in, const int* in_sizes, int n_in,
                              void* d_out, int out_size, void* d_ws, size_t ws_size,
                              hipStream_t stream) {
    const float* x       = (const float*)d_in[0];
    const float* prev    = (const float*)d_in[1];
    const float* istyle  = (const float*)d_in[2];
    const float* W_style = (const float*)d_in[3];
    const float* b_style = (const float*)d_in[4];
    const float* wk      = (const float*)d_in[5];  // conv_weight flat = (C,)
    float* ws    = (float*)d_ws;
    float* coef  = ws;          // 1024 floats
    float* small = ws + 1024;   // BATCH*SVOL floats

    coef_kernel<<<256, 256, 0, stream>>>(istyle, W_style, b_style, wk, coef);

    reduce_c_kernel<<<BATCH * SV4 / TILE, 256, 0, stream>>>(
        (const floatx4*)x, coef, (const floatx4*)prev, (floatx4*)small);

    upblur_kernel<<<BATCH * 32768 / 256, 256, 0, stream>>>(small, (float*)d_out);
}